// Round 13
// baseline (467.965 us; speedup 1.0000x reference)
//
#include <hip/hip_runtime.h>
#include <hip/hip_bf16.h>

#define BATCH 256
#define NDIM  4096
#define STEPS 16
#define EPS_RMS 1.1920929e-07f

typedef _Float16 f16x8 __attribute__((ext_vector_type(8)));
typedef float  f32x4  __attribute__((ext_vector_type(4)));
typedef unsigned short u16x4 __attribute__((ext_vector_type(4)));
typedef unsigned short u16x8 __attribute__((ext_vector_type(8)));

#define AS1 __attribute__((address_space(1)))
#define AS3 __attribute__((address_space(3)))
#define GLDS16(gp, lp) __builtin_amdgcn_global_load_lds( \
    (const AS1 void*)(gp), (AS3 void*)(lp), 16, 0, 0)
#define SBAR() do { asm volatile("" ::: "memory"); \
                    __builtin_amdgcn_s_barrier();  \
                    asm volatile("" ::: "memory"); } while (0)

__device__ __forceinline__ unsigned short f2h(float f) {
  _Float16 h = (_Float16)f;
  union { _Float16 h; unsigned short u; } v; v.h = h; return v.u;
}
__device__ __forceinline__ float h2f(unsigned short u) {
  union { unsigned short u; _Float16 h; } v; v.u = u; return (float)v.h;
}

__device__ __forceinline__ float block_reduce_sum_512(float v) {
  __shared__ float ws[8];
  __shared__ float tot;
  #pragma unroll
  for (int off = 32; off > 0; off >>= 1) v += __shfl_down(v, off, 64);
  int lane = threadIdx.x & 63, w = threadIdx.x >> 6;
  if (lane == 0) ws[w] = v;
  __syncthreads();
  if (threadIdx.x == 0) {
    float t = 0.f;
    #pragma unroll
    for (int i = 0; i < 8; ++i) t += ws[i];
    tot = t;
  }
  __syncthreads();
  return tot;
}

// ------- W (f32,[k][n]) -> Wt (fp16,[n][k]); y==0 blocks also fill icm/ocm -------
__global__ __launch_bounds__(256) void transpose_w(
    const float* __restrict__ W, unsigned short* __restrict__ Wt,
    const float* __restrict__ iscale, const float* __restrict__ oscale,
    const int* __restrict__ ipos, const int* __restrict__ opos,
    float* __restrict__ icm, float* __restrict__ ocm) {
  __shared__ float tile[64][65];
  int n0 = blockIdx.x * 64;
  int k0 = blockIdx.y * 64;
  int t = threadIdx.x;
  if (blockIdx.y == 0 && t < 64) {
    int c = n0 + t;
    float iv = 1.f, ov = 1.f;
    #pragma unroll
    for (int i = 0; i < 16; ++i) {
      if (ipos[i] == c) iv *= iscale[i];
      if (opos[i] == c) ov *= oscale[i];
    }
    icm[c] = iv; ocm[c] = ov;
  }
  int r = t >> 4, c4 = (t & 15) * 4;
  #pragma unroll
  for (int p = 0; p < 4; ++p) {
    f32x4 v = *(const f32x4*)(W + (size_t)(k0 + r + 16 * p) * NDIM + n0 + c4);
    tile[r + 16 * p][c4 + 0] = v[0];
    tile[r + 16 * p][c4 + 1] = v[1];
    tile[r + 16 * p][c4 + 2] = v[2];
    tile[r + 16 * p][c4 + 3] = v[3];
  }
  __syncthreads();
  #pragma unroll
  for (int p = 0; p < 4; ++p) {
    int nr = r + 16 * p;
    u16x4 o;
    #pragma unroll
    for (int j = 0; j < 4; ++j) o[j] = f2h(tile[c4 + j][nr]);
    *(u16x4*)(Wt + (size_t)(n0 + nr) * NDIM + k0 + c4) = o;
  }
}

// ---------------- step 0: h1 = norm(tanh(B + x*icm)); h only ----------------
__global__ __launch_bounds__(512) void step0_kernel(
    const float* __restrict__ x, const float* __restrict__ bias,
    const float* __restrict__ icm, const float* __restrict__ nw,
    unsigned short* __restrict__ hbuf) {
  int row = blockIdx.x;
  int tid = threadIdx.x;
  const float* xr = x + (size_t)row * NDIM;
  float a[8];
  float sq = 0.f;
  #pragma unroll
  for (int p = 0; p < 2; ++p) {
    int c = p * 2048 + tid * 4;
    f32x4 xv = *(const f32x4*)(xr + c);
    f32x4 bv = *(const f32x4*)(bias + c);
    f32x4 ic = *(const f32x4*)(icm + c);
    #pragma unroll
    for (int j = 0; j < 4; ++j) {
      float av = tanhf(bv[j] + xv[j] * ic[j]);
      a[p * 4 + j] = av;
      sq += av * av;
    }
  }
  float tot = block_reduce_sum_512(sq);
  float scale = rsqrtf(tot * (1.0f / NDIM) + EPS_RMS);
  unsigned short* hrow = hbuf + (size_t)row * NDIM;
  #pragma unroll
  for (int p = 0; p < 2; ++p) {
    int c = p * 2048 + tid * 4;
    f32x4 nv = *(const f32x4*)(nw + c);
    u16x4 hs;
    #pragma unroll
    for (int j = 0; j < 4; ++j) hs[j] = f2h(a[p * 4 + j] * scale * nv[j]);
    *(u16x4*)(hrow + c) = hs;
  }
}

// ---- GEMM: pbuf[ks] = (h @ W)[128x128 tile, K-slice kslen] fp16 out.
// R11-verified engine (GLDS16 staging, involution swizzle, LDS dbuf, counted
// vmcnt(8)); kslen=256 -> grid (32,2,16) = 1024 blocks = 4 blocks/CU.
// Also writes out[:, t-1, :] strip (128 rows x kslen/32 cols, L2-hot h).
template <int MINW>
__global__ __launch_bounds__(256, MINW) void gemm_kernel(
    const unsigned short* __restrict__ A,   // h_{t-1} fp16 [256][4096]
    const unsigned short* __restrict__ Bt,  // Wt fp16 [n][k]
    unsigned short* __restrict__ pbuf,      // [ksplit][256][4096] fp16
    const float* __restrict__ ocm,
    float* __restrict__ out, int kslen, int tm1) {
  __shared__ __align__(16) unsigned short As[2][128 * 64];
  __shared__ __align__(16) unsigned short Bs[2][128 * 64];
  const int tid = threadIdx.x;
  const int n0 = blockIdx.x * 128;
  const int m0 = blockIdx.y * 128;
  const int ks = blockIdx.z;
  const int kbase = ks * kslen;
  const int nit = kslen >> 6;
  const int wave = tid >> 6, lane = tid & 63;
  const int wm = (wave >> 1) * 64, wn = (wave & 1) * 64;
  const int l15 = lane & 15;
  const int g = lane >> 4;               // 0..3 k-group
  const int q = l15 & 7;                 // read-side swizzle key (row&7)
  const int srow = tid >> 3;             // 0..31 staging row-in-group
  const int sch = tid & 7;               // staging chunk
  const int koff = (sch ^ (srow & 7)) * 8;  // involution-swizzled k offset

  const unsigned short* aP[4];
  const unsigned short* bP[4];
  #pragma unroll
  for (int i = 0; i < 4; ++i) {
    aP[i] = A + (size_t)(m0 + i * 32 + srow) * NDIM + kbase + koff;
    bP[i] = Bt + (size_t)(n0 + i * 32 + srow) * NDIM + kbase + koff;
  }

  f32x4 acc[4][4];
  f32x4 zero = {0.f, 0.f, 0.f, 0.f};
  #pragma unroll
  for (int i = 0; i < 4; ++i)
    #pragma unroll
    for (int j = 0; j < 4; ++j) acc[i][j] = zero;

  // prologue: stage k-tile 0 into buffer 0
  #pragma unroll
  for (int i = 0; i < 4; ++i)
    GLDS16(aP[i], &As[0][(i * 32 + srow) * 64 + sch * 8]);
  #pragma unroll
  for (int i = 0; i < 4; ++i)
    GLDS16(bP[i], &Bs[0][(i * 32 + srow) * 64 + sch * 8]);

  for (int it = 0; it < nit; ++it) {
    const int p = it & 1;
    SBAR();   // all waves done reading buf[1-p]
    if (it < nit - 1) {
      const int kb = (it + 1) * 64;
      #pragma unroll
      for (int i = 0; i < 4; ++i)
        GLDS16(aP[i] + kb, &As[1 - p][(i * 32 + srow) * 64 + sch * 8]);
      #pragma unroll
      for (int i = 0; i < 4; ++i)
        GLDS16(bP[i] + kb, &Bs[1 - p][(i * 32 + srow) * 64 + sch * 8]);
      asm volatile("s_waitcnt vmcnt(8)" ::: "memory");  // tile `it` landed
    } else {
      asm volatile("s_waitcnt vmcnt(0)" ::: "memory");
    }
    SBAR();   // tile `it` visible to all waves
    #pragma unroll
    for (int kk = 0; kk < 2; ++kk) {
      f16x8 af[4], bfr[4];
      #pragma unroll
      for (int mf = 0; mf < 4; ++mf) {
        int row = wm + mf * 16 + l15;
        af[mf] = *(const f16x8*)&As[p][row * 64 + (((kk << 2) + g) ^ q) * 8];
      }
      #pragma unroll
      for (int nf = 0; nf < 4; ++nf) {
        int row = wn + nf * 16 + l15;
        bfr[nf] = *(const f16x8*)&Bs[p][row * 64 + (((kk << 2) + g) ^ q) * 8];
      }
      #pragma unroll
      for (int mf = 0; mf < 4; ++mf)
        #pragma unroll
        for (int nf = 0; nf < 4; ++nf)
          acc[mf][nf] = __builtin_amdgcn_mfma_f32_16x16x32_f16(af[mf], bfr[nf], acc[mf][nf], 0, 0, 0);
    }
  }

  {
    unsigned short* pout = pbuf + (size_t)ks * BATCH * NDIM;
    const int crow = g * 4;
    #pragma unroll
    for (int mf = 0; mf < 4; ++mf) {
      #pragma unroll
      for (int nf = 0; nf < 4; ++nf) {
        int col = n0 + wn + nf * 16 + l15;
        #pragma unroll
        for (int r = 0; r < 4; ++r) {
          int row = m0 + wm + mf * 16 + crow + r;
          pout[(size_t)row * NDIM + col] = f2h(acc[mf][nf][r]);
        }
      }
    }
  }

  // ---- out[:, t-1, :] strip: rows m0..m0+127, cols kbase + x*cw .. +cw-1 ----
  {
    const int cw = kslen >> 5;                 // 16 (ksplit8) or 8 (ksplit16)
    const int col0 = kbase + blockIdx.x * cw;
    const int row = m0 + (tid >> 1);
    for (int j4 = 0; j4 < (cw >> 3); ++j4) {
      const int c4 = (tid & 1) * 4 + j4 * 8;
      u16x4 hv = *(const u16x4*)(A + (size_t)row * NDIM + col0 + c4);
      f32x4 oc = *(const f32x4*)(ocm + col0 + c4);
      f32x4 o;
      #pragma unroll
      for (int j = 0; j < 4; ++j) o[j] = h2f(hv[j]) * oc[j];
      *(f32x4*)(out + ((size_t)row * STEPS + tm1) * NDIM + col0 + c4) = o;
    }
  }
}

// ------- combine fp16 splits + bias + tanh + RMSNorm -> h_t; last: out+hfin -------
__global__ __launch_bounds__(512) void normalize_kernel(
    const unsigned short* __restrict__ pbuf, const float* __restrict__ bias,
    const float* __restrict__ nw, const float* __restrict__ ocm,
    unsigned short* __restrict__ hbuf, float* __restrict__ out,
    float* __restrict__ hfin, int is_last, int ksplit) {
  const size_t SL = (size_t)BATCH * NDIM;
  int row = blockIdx.x;
  int tid = threadIdx.x;
  int c = tid * 8;
  const unsigned short* p0 = pbuf + (size_t)row * NDIM + c;
  float s[8];
  {
    const float* b0 = bias + c;
    #pragma unroll
    for (int j = 0; j < 8; ++j) s[j] = b0[j];
  }
  for (int k = 0; k < ksplit; ++k) {
    u16x8 v = *(const u16x8*)(p0 + (size_t)k * SL);
    #pragma unroll
    for (int j = 0; j < 8; ++j) s[j] += h2f(v[j]);
  }
  float a[8];
  float sq = 0.f;
  #pragma unroll
  for (int j = 0; j < 8; ++j) {
    float av = tanhf(s[j]);
    a[j] = av;
    sq += av * av;
  }
  float tot = block_reduce_sum_512(sq);
  float scale = rsqrtf(tot * (1.0f / NDIM) + EPS_RMS);
  unsigned short* hrow = hbuf + (size_t)row * NDIM + c;
  const float* nv = nw + c;
  u16x8 hs;
  if (is_last) {
    float* orow = out + ((size_t)row * STEPS + (STEPS - 1)) * NDIM + c;
    float* frow = hfin + (size_t)row * NDIM + c;
    const float* oc = ocm + c;
    #pragma unroll
    for (int j = 0; j < 8; ++j) {
      float h = a[j] * scale * nv[j];
      hs[j] = f2h(h);
      orow[j] = h * oc[j];
      frow[j] = h;
    }
  } else {
    #pragma unroll
    for (int j = 0; j < 8; ++j) hs[j] = f2h(a[j] * scale * nv[j]);
  }
  *(u16x8*)hrow = hs;
}

extern "C" void kernel_launch(void* const* d_in, const int* in_sizes, int n_in,
                              void* d_out, int out_size, void* d_ws, size_t ws_size,
                              hipStream_t stream) {
  (void)in_sizes; (void)n_in; (void)out_size;
  const float* x      = (const float*)d_in[0];
  const float* W      = (const float*)d_in[1];
  const float* Bb     = (const float*)d_in[2];
  const float* iscale = (const float*)d_in[3];
  const float* oscale = (const float*)d_in[4];
  const float* nw     = (const float*)d_in[5];
  const int* ipos = (const int*)d_in[6];
  const int* opos = (const int*)d_in[7];
  // d_in[8] = steps (fixed at 16 by the problem spec).

  char* ws = (char*)d_ws;
  unsigned short* Wt   = (unsigned short*)(ws);             // 32 MiB fp16
  unsigned short* hA   = (unsigned short*)(ws + 33554432);  // 2 MiB fp16
  unsigned short* hB   = (unsigned short*)(ws + 35651584);  // 2 MiB fp16
  float* icm           = (float*)(ws + 37748736);           // 16 KiB
  float* ocm           = (float*)(ws + 37765120);           // 16 KiB
  unsigned short* pbuf = (unsigned short*)(ws + 37781504);  // up to 32 MiB fp16

  // ksplit=16 (4 blocks/CU) needs pbuf 32 MiB -> ~68 MiB total; else R11 config.
  size_t need16 = 37781504 + (size_t)16 * BATCH * NDIM * sizeof(unsigned short);
  int ksplit = (ws_size >= need16) ? 16 : 8;
  int kslen = NDIM / ksplit;

  float* out  = (float*)d_out;
  float* hfin = out + (size_t)BATCH * STEPS * NDIM;

  hipLaunchKernelGGL(transpose_w, dim3(64, 64), dim3(256), 0, stream,
                     W, Wt, iscale, oscale, ipos, opos, icm, ocm);
  hipLaunchKernelGGL(step0_kernel, dim3(256), dim3(512), 0, stream,
                     x, Bb, icm, nw, hA);
  for (int t = 1; t < STEPS; ++t) {
    const unsigned short* Ap = ((t - 1) & 1) ? hB : hA;
    unsigned short* Ac = (t & 1) ? hB : hA;
    if (ksplit == 16) {
      hipLaunchKernelGGL(gemm_kernel<4>, dim3(32, 2, 16), dim3(256), 0, stream,
                         Ap, Wt, pbuf, ocm, out, kslen, t - 1);
    } else {
      hipLaunchKernelGGL(gemm_kernel<2>, dim3(32, 2, 8), dim3(256), 0, stream,
                         Ap, Wt, pbuf, ocm, out, kslen, t - 1);
    }
    hipLaunchKernelGGL(normalize_kernel, dim3(256), dim3(512), 0, stream,
                       pbuf, Bb, nw, ocm, Ac, out, hfin,
                       (t == STEPS - 1) ? 1 : 0, ksplit);
  }
}

// Round 14
// 337.252 us; speedup vs baseline: 1.3876x; 1.3876x over previous
//
#include <hip/hip_runtime.h>
#include <hip/hip_bf16.h>

#define BATCH 256
#define NDIM  4096
#define STEPS 16
#define EPS_RMS 1.1920929e-07f

typedef _Float16 f16x8 __attribute__((ext_vector_type(8)));
typedef float  f32x4  __attribute__((ext_vector_type(4)));
typedef unsigned short u16x4 __attribute__((ext_vector_type(4)));
typedef unsigned short u16x8 __attribute__((ext_vector_type(8)));

#define AS1 __attribute__((address_space(1)))
#define AS3 __attribute__((address_space(3)))
#define GLDS16(gp, lp) __builtin_amdgcn_global_load_lds( \
    (const AS1 void*)(gp), (AS3 void*)(lp), 16, 0, 0)
#define SBAR() do { asm volatile("" ::: "memory"); \
                    __builtin_amdgcn_s_barrier();  \
                    asm volatile("" ::: "memory"); } while (0)

__device__ __forceinline__ unsigned short f2h(float f) {
  _Float16 h = (_Float16)f;
  union { _Float16 h; unsigned short u; } v; v.h = h; return v.u;
}
__device__ __forceinline__ float h2f(unsigned short u) {
  union { unsigned short u; _Float16 h; } v; v.u = u; return (float)v.h;
}

__device__ __forceinline__ float block_reduce_sum_512(float v) {
  __shared__ float ws[8];
  __shared__ float tot;
  #pragma unroll
  for (int off = 32; off > 0; off >>= 1) v += __shfl_down(v, off, 64);
  int lane = threadIdx.x & 63, w = threadIdx.x >> 6;
  if (lane == 0) ws[w] = v;
  __syncthreads();
  if (threadIdx.x == 0) {
    float t = 0.f;
    #pragma unroll
    for (int i = 0; i < 8; ++i) t += ws[i];
    tot = t;
  }
  __syncthreads();
  return tot;
}

__device__ __forceinline__ float block_reduce_sum_1024(float v) {
  __shared__ float ws[16];
  __shared__ float tot;
  #pragma unroll
  for (int off = 32; off > 0; off >>= 1) v += __shfl_down(v, off, 64);
  int lane = threadIdx.x & 63, w = threadIdx.x >> 6;
  if (lane == 0) ws[w] = v;
  __syncthreads();
  if (threadIdx.x == 0) {
    float t = 0.f;
    #pragma unroll
    for (int i = 0; i < 16; ++i) t += ws[i];
    tot = t;
  }
  __syncthreads();
  return tot;
}

// ------- W (f32,[k][n]) -> Wt (fp16,[n][k]); y==0 blocks also fill icm/ocm -------
__global__ __launch_bounds__(256) void transpose_w(
    const float* __restrict__ W, unsigned short* __restrict__ Wt,
    const float* __restrict__ iscale, const float* __restrict__ oscale,
    const int* __restrict__ ipos, const int* __restrict__ opos,
    float* __restrict__ icm, float* __restrict__ ocm) {
  __shared__ float tile[64][65];
  int n0 = blockIdx.x * 64;
  int k0 = blockIdx.y * 64;
  int t = threadIdx.x;
  if (blockIdx.y == 0 && t < 64) {
    int c = n0 + t;
    float iv = 1.f, ov = 1.f;
    #pragma unroll
    for (int i = 0; i < 16; ++i) {
      if (ipos[i] == c) iv *= iscale[i];
      if (opos[i] == c) ov *= oscale[i];
    }
    icm[c] = iv; ocm[c] = ov;
  }
  int r = t >> 4, c4 = (t & 15) * 4;
  #pragma unroll
  for (int p = 0; p < 4; ++p) {
    f32x4 v = *(const f32x4*)(W + (size_t)(k0 + r + 16 * p) * NDIM + n0 + c4);
    tile[r + 16 * p][c4 + 0] = v[0];
    tile[r + 16 * p][c4 + 1] = v[1];
    tile[r + 16 * p][c4 + 2] = v[2];
    tile[r + 16 * p][c4 + 3] = v[3];
  }
  __syncthreads();
  #pragma unroll
  for (int p = 0; p < 4; ++p) {
    int nr = r + 16 * p;
    u16x4 o;
    #pragma unroll
    for (int j = 0; j < 4; ++j) o[j] = f2h(tile[c4 + j][nr]);
    *(u16x4*)(Wt + (size_t)(n0 + nr) * NDIM + k0 + c4) = o;
  }
}

// ---------------- step 0: h1 = norm(tanh(B + x*icm)); h only ----------------
__global__ __launch_bounds__(512) void step0_kernel(
    const float* __restrict__ x, const float* __restrict__ bias,
    const float* __restrict__ icm, const float* __restrict__ nw,
    unsigned short* __restrict__ hbuf) {
  int row = blockIdx.x;
  int tid = threadIdx.x;
  const float* xr = x + (size_t)row * NDIM;
  float a[8];
  float sq = 0.f;
  #pragma unroll
  for (int p = 0; p < 2; ++p) {
    int c = p * 2048 + tid * 4;
    f32x4 xv = *(const f32x4*)(xr + c);
    f32x4 bv = *(const f32x4*)(bias + c);
    f32x4 ic = *(const f32x4*)(icm + c);
    #pragma unroll
    for (int j = 0; j < 4; ++j) {
      float av = tanhf(bv[j] + xv[j] * ic[j]);
      a[p * 4 + j] = av;
      sq += av * av;
    }
  }
  float tot = block_reduce_sum_512(sq);
  float scale = rsqrtf(tot * (1.0f / NDIM) + EPS_RMS);
  unsigned short* hrow = hbuf + (size_t)row * NDIM;
  #pragma unroll
  for (int p = 0; p < 2; ++p) {
    int c = p * 2048 + tid * 4;
    f32x4 nv = *(const f32x4*)(nw + c);
    u16x4 hs;
    #pragma unroll
    for (int j = 0; j < 4; ++j) hs[j] = f2h(a[p * 4 + j] * scale * nv[j]);
    *(u16x4*)(hrow + c) = hs;
  }
}

// ---- GEMM: pbuf[ks] = (h @ W)[128x128 tile, K-slice 512] fp16 out.
// R11 champion engine: GLDS16 staging, involution swizzle, LDS dbuf,
// counted vmcnt(8). grid (32, 2, 8) = 512 blocks (2/CU, 8 waves/CU).
// Also writes out[:, t-1, :] for its 128-row x 16-col strip (L2-hot h).
__global__ __launch_bounds__(256, 2) void gemm_kernel(
    const unsigned short* __restrict__ A,   // h_{t-1} fp16 [256][4096]
    const unsigned short* __restrict__ Bt,  // Wt fp16 [n][k]
    unsigned short* __restrict__ pbuf,      // [8][256][4096] fp16
    const float* __restrict__ ocm,
    float* __restrict__ out, int tm1) {
  __shared__ __align__(16) unsigned short As[2][128 * 64];
  __shared__ __align__(16) unsigned short Bs[2][128 * 64];
  const int tid = threadIdx.x;
  const int n0 = blockIdx.x * 128;
  const int m0 = blockIdx.y * 128;
  const int ks = blockIdx.z;
  const int kbase = ks * 512;
  const int wave = tid >> 6, lane = tid & 63;
  const int wm = (wave >> 1) * 64, wn = (wave & 1) * 64;
  const int l15 = lane & 15;
  const int g = lane >> 4;               // 0..3 k-group
  const int q = l15 & 7;                 // read-side swizzle key (row&7)
  const int srow = tid >> 3;             // 0..31 staging row-in-group
  const int sch = tid & 7;               // staging chunk
  const int koff = (sch ^ (srow & 7)) * 8;  // involution-swizzled k offset

  const unsigned short* aP[4];
  const unsigned short* bP[4];
  #pragma unroll
  for (int i = 0; i < 4; ++i) {
    aP[i] = A + (size_t)(m0 + i * 32 + srow) * NDIM + kbase + koff;
    bP[i] = Bt + (size_t)(n0 + i * 32 + srow) * NDIM + kbase + koff;
  }

  f32x4 acc[4][4];
  f32x4 zero = {0.f, 0.f, 0.f, 0.f};
  #pragma unroll
  for (int i = 0; i < 4; ++i)
    #pragma unroll
    for (int j = 0; j < 4; ++j) acc[i][j] = zero;

  // prologue: stage k-tile 0 into buffer 0
  #pragma unroll
  for (int i = 0; i < 4; ++i)
    GLDS16(aP[i], &As[0][(i * 32 + srow) * 64 + sch * 8]);
  #pragma unroll
  for (int i = 0; i < 4; ++i)
    GLDS16(bP[i], &Bs[0][(i * 32 + srow) * 64 + sch * 8]);

  for (int it = 0; it < 8; ++it) {
    const int p = it & 1;
    SBAR();   // all waves done reading buf[1-p]
    if (it < 7) {
      const int kb = (it + 1) * 64;
      #pragma unroll
      for (int i = 0; i < 4; ++i)
        GLDS16(aP[i] + kb, &As[1 - p][(i * 32 + srow) * 64 + sch * 8]);
      #pragma unroll
      for (int i = 0; i < 4; ++i)
        GLDS16(bP[i] + kb, &Bs[1 - p][(i * 32 + srow) * 64 + sch * 8]);
      asm volatile("s_waitcnt vmcnt(8)" ::: "memory");  // tile `it` landed
    } else {
      asm volatile("s_waitcnt vmcnt(0)" ::: "memory");
    }
    SBAR();   // tile `it` visible to all waves
    #pragma unroll
    for (int kk = 0; kk < 2; ++kk) {
      f16x8 af[4], bfr[4];
      #pragma unroll
      for (int mf = 0; mf < 4; ++mf) {
        int row = wm + mf * 16 + l15;
        af[mf] = *(const f16x8*)&As[p][row * 64 + (((kk << 2) + g) ^ q) * 8];
      }
      #pragma unroll
      for (int nf = 0; nf < 4; ++nf) {
        int row = wn + nf * 16 + l15;
        bfr[nf] = *(const f16x8*)&Bs[p][row * 64 + (((kk << 2) + g) ^ q) * 8];
      }
      #pragma unroll
      for (int mf = 0; mf < 4; ++mf)
        #pragma unroll
        for (int nf = 0; nf < 4; ++nf)
          acc[mf][nf] = __builtin_amdgcn_mfma_f32_16x16x32_f16(af[mf], bfr[nf], acc[mf][nf], 0, 0, 0);
    }
  }

  {
    unsigned short* pout = pbuf + (size_t)ks * BATCH * NDIM;
    const int crow = g * 4;
    #pragma unroll
    for (int mf = 0; mf < 4; ++mf) {
      #pragma unroll
      for (int nf = 0; nf < 4; ++nf) {
        int col = n0 + wn + nf * 16 + l15;
        #pragma unroll
        for (int r = 0; r < 4; ++r) {
          int row = m0 + wm + mf * 16 + crow + r;
          pout[(size_t)row * NDIM + col] = f2h(acc[mf][nf][r]);
        }
      }
    }
  }

  // ---- out[:, t-1, :] strip: rows m0..m0+127, cols kbase + x*16 .. +15 ----
  {
    const int col0 = kbase + blockIdx.x * 16;
    const int row = m0 + (tid >> 1);
    const int c8 = (tid & 1) * 8;
    u16x8 hv = *(const u16x8*)(A + (size_t)row * NDIM + col0 + c8);
    f32x4 oc0 = *(const f32x4*)(ocm + col0 + c8);
    f32x4 oc1 = *(const f32x4*)(ocm + col0 + c8 + 4);
    f32x4 o0, o1;
    #pragma unroll
    for (int j = 0; j < 4; ++j) {
      o0[j] = h2f(hv[j]) * oc0[j];
      o1[j] = h2f(hv[j + 4]) * oc1[j];
    }
    float* orow = out + ((size_t)row * STEPS + tm1) * NDIM + col0 + c8;
    *(f32x4*)orow = o0;
    *(f32x4*)(orow + 4) = o1;
  }
}

// ------- combine 8 fp16 splits + bias + tanh + RMSNorm -> h_t; last: out+hfin -------
// 1024 threads/block (16 waves/CU at 1 block/CU), 4 columns per thread.
__global__ __launch_bounds__(1024) void normalize_kernel(
    const unsigned short* __restrict__ pbuf, const float* __restrict__ bias,
    const float* __restrict__ nw, const float* __restrict__ ocm,
    unsigned short* __restrict__ hbuf, float* __restrict__ out,
    float* __restrict__ hfin, int is_last) {
  const size_t SL = (size_t)BATCH * NDIM;
  int row = blockIdx.x;
  int tid = threadIdx.x;
  int c = tid * 4;
  const unsigned short* p0 = pbuf + (size_t)row * NDIM + c;
  float s[4];
  {
    f32x4 bv = *(const f32x4*)(bias + c);
    #pragma unroll
    for (int j = 0; j < 4; ++j) s[j] = bv[j];
  }
  #pragma unroll
  for (int k = 0; k < 8; ++k) {
    u16x4 v = *(const u16x4*)(p0 + (size_t)k * SL);
    #pragma unroll
    for (int j = 0; j < 4; ++j) s[j] += h2f(v[j]);
  }
  float a[4];
  float sq = 0.f;
  #pragma unroll
  for (int j = 0; j < 4; ++j) {
    float av = tanhf(s[j]);
    a[j] = av;
    sq += av * av;
  }
  float tot = block_reduce_sum_1024(sq);
  float scale = rsqrtf(tot * (1.0f / NDIM) + EPS_RMS);
  unsigned short* hrow = hbuf + (size_t)row * NDIM + c;
  const float* nv = nw + c;
  u16x4 hs;
  if (is_last) {
    float* orow = out + ((size_t)row * STEPS + (STEPS - 1)) * NDIM + c;
    float* frow = hfin + (size_t)row * NDIM + c;
    const float* oc = ocm + c;
    #pragma unroll
    for (int j = 0; j < 4; ++j) {
      float h = a[j] * scale * nv[j];
      hs[j] = f2h(h);
      orow[j] = h * oc[j];
      frow[j] = h;
    }
  } else {
    #pragma unroll
    for (int j = 0; j < 4; ++j) hs[j] = f2h(a[j] * scale * nv[j]);
  }
  *(u16x4*)hrow = hs;
}

extern "C" void kernel_launch(void* const* d_in, const int* in_sizes, int n_in,
                              void* d_out, int out_size, void* d_ws, size_t ws_size,
                              hipStream_t stream) {
  (void)in_sizes; (void)n_in; (void)out_size; (void)ws_size;
  const float* x      = (const float*)d_in[0];
  const float* W      = (const float*)d_in[1];
  const float* Bb     = (const float*)d_in[2];
  const float* iscale = (const float*)d_in[3];
  const float* oscale = (const float*)d_in[4];
  const float* nw     = (const float*)d_in[5];
  const int* ipos = (const int*)d_in[6];
  const int* opos = (const int*)d_in[7];
  // d_in[8] = steps (fixed at 16 by the problem spec).

  char* ws = (char*)d_ws;
  unsigned short* Wt   = (unsigned short*)(ws);             // 32 MiB fp16
  unsigned short* hA   = (unsigned short*)(ws + 33554432);  // 2 MiB fp16
  unsigned short* hB   = (unsigned short*)(ws + 35651584);  // 2 MiB fp16
  float* icm           = (float*)(ws + 37748736);           // 16 KiB
  float* ocm           = (float*)(ws + 37765120);           // 16 KiB
  unsigned short* pbuf = (unsigned short*)(ws + 37781504);  // 16 MiB fp16 (8 slices)

  float* out  = (float*)d_out;
  float* hfin = out + (size_t)BATCH * STEPS * NDIM;

  hipLaunchKernelGGL(transpose_w, dim3(64, 64), dim3(256), 0, stream,
                     W, Wt, iscale, oscale, ipos, opos, icm, ocm);
  hipLaunchKernelGGL(step0_kernel, dim3(256), dim3(512), 0, stream,
                     x, Bb, icm, nw, hA);
  for (int t = 1; t < STEPS; ++t) {
    const unsigned short* Ap = ((t - 1) & 1) ? hB : hA;
    unsigned short* Ac = (t & 1) ? hB : hA;
    hipLaunchKernelGGL(gemm_kernel, dim3(32, 2, 8), dim3(256), 0, stream,
                       Ap, Wt, pbuf, ocm, out, t - 1);
    hipLaunchKernelGGL(normalize_kernel, dim3(256), dim3(1024), 0, stream,
                       pbuf, Bb, nw, ocm, Ac, out, hfin, (t == STEPS - 1) ? 1 : 0);
  }
}